// Round 4
// baseline (249.099 us; speedup 1.0000x reference)
//
#include <hip/hip_runtime.h>

#define IN_CH 256
#define IMG_H 56
#define IMG_W 56
#define NBATCH 32
#define BPG 4               // batches (tiles) per block
#define GY (NBATCH / BPG)   // 8 batch-groups

typedef float v4f __attribute__((ext_vector_type(4)));

// out[b,c0] = conv3x3(x[b,c0], w[2c0]) + conv3x3(x[b,c1], w[2c1+1]),  c1 = c0^4
// out[b,c1] = conv3x3(x[b,c1], w[2c1]) + conv3x3(x[b,c0], w[2c0+1])
// Block (p, g): channel pair p, batches {g, g+8, g+16, g+24}, software-pipelined
// with two alternating register buffers so tile t+1's loads fly during tile t's compute.
__global__ __launch_bounds__(256, 4) void dwconv_butterfly(
    const float* __restrict__ x, const float* __restrict__ wgt,
    float* __restrict__ out)
{
    const int tid = threadIdx.x;
    const int s   = tid >> 4;            // row-strip 0..15 (active < 14)
    const int i   = tid & 15;            // col-quad  0..15 (active < 14)
    const bool active = (s < 14) && (i < 14);
    const int ss  = (s < 14) ? s : 13;   // clamp inactive lanes onto valid addresses
    const int ii  = (i < 14) ? i : 13;

    const int p  = blockIdx.x;           // 0..127
    const int g  = blockIdx.y;           // 0..7
    const int c0 = ((p >> 2) << 3) | (p & 3);   // bit2 == 0
    const int c1 = c0 ^ 4;

    const size_t chan = (size_t)IMG_H * IMG_W;  // 3136

    // Weights: wave-uniform -> scalar loads, reused across 4 tiles.
    float wa[9], wb[9], wc[9], wd[9];
    {
        const float* pa = wgt + (size_t)(2 * c0) * 9;
        const float* pb = wgt + (size_t)(2 * c1 + 1) * 9;
        const float* pc = wgt + (size_t)(2 * c1) * 9;
        const float* pd = wgt + (size_t)(2 * c0) * 9 + 9;   // w[2c0+1]
#pragma unroll
        for (int k = 0; k < 9; ++k) {
            wa[k] = pa[k]; wb[k] = pb[k]; wc[k] = pc[k]; wd[k] = pd[k];
        }
    }

    const int row0 = 4 * ss - 1;         // first input row this thread touches
    const int col  = 4 * ii;

    // Per-row clamped offsets + out-of-range flags (shared by all 4 tiles).
    int  roff[6];
    bool zrow[6];
#pragma unroll
    for (int k = 0; k < 6; ++k) {
        const int rr = row0 + k;
        zrow[k] = (rr < 0) || (rr >= IMG_H);
        const int rc = rr < 0 ? 0 : (rr >= IMG_H ? IMG_H - 1 : rr);
        roff[k] = rc * IMG_W + col;
    }

    // Pure load phase: 12 unconditional back-to-back dwordx4 loads.
    auto load_tile = [&](int b, float4* v0, float4* v1) {
        const float* x0 = x + ((size_t)b * IN_CH + c0) * chan;
        const float* x1 = x + ((size_t)b * IN_CH + c1) * chan;
#pragma unroll
        for (int k = 0; k < 6; ++k) {
            v0[k] = *(const float4*)(x0 + roff[k]);
            v1[k] = *(const float4*)(x1 + roff[k]);
        }
    };

    auto compute_tile = [&](int b, const float4* v0, const float4* v1) {
        // Halo columns from neighbor lanes (permute pipe, no LDS/barrier).
        float l0[6], r0h[6], l1[6], r1h[6];
#pragma unroll
        for (int k = 0; k < 6; ++k) {
            const float a  = __shfl_up(v0[k].w, 1);
            const float bb = __shfl_up(v1[k].w, 1);
            const float c  = __shfl_down(v0[k].x, 1);
            const float d  = __shfl_down(v1[k].x, 1);
            l0[k]  = (i == 0)  ? 0.f : a;
            l1[k]  = (i == 0)  ? 0.f : bb;
            r0h[k] = (i == 13) ? 0.f : c;
            r1h[k] = (i == 13) ? 0.f : d;
        }

        float* o0 = out + ((size_t)b * IN_CH + c0) * chan;
        float* o1 = out + ((size_t)b * IN_CH + c1) * chan;

#pragma unroll
        for (int m = 0; m < 4; ++m) {
            float acc0[4] = {0.f, 0.f, 0.f, 0.f};
            float acc1[4] = {0.f, 0.f, 0.f, 0.f};
#pragma unroll
            for (int kh = 0; kh < 3; ++kh) {
                const int k = m + kh;
                const float z = zrow[k] ? 0.f : 1.f;  // folds into one extra mul path; rows
                // out-of-range must contribute 0 (zero padding).
                const float e0[6] = {zrow[k] ? 0.f : l0[k],
                                     zrow[k] ? 0.f : v0[k].x, zrow[k] ? 0.f : v0[k].y,
                                     zrow[k] ? 0.f : v0[k].z, zrow[k] ? 0.f : v0[k].w,
                                     zrow[k] ? 0.f : r0h[k]};
                const float e1[6] = {zrow[k] ? 0.f : l1[k],
                                     zrow[k] ? 0.f : v1[k].x, zrow[k] ? 0.f : v1[k].y,
                                     zrow[k] ? 0.f : v1[k].z, zrow[k] ? 0.f : v1[k].w,
                                     zrow[k] ? 0.f : r1h[k]};
                (void)z;
#pragma unroll
                for (int kw = 0; kw < 3; ++kw) {
                    const float fa = wa[kh * 3 + kw], fb = wb[kh * 3 + kw];
                    const float fc = wc[kh * 3 + kw], fd = wd[kh * 3 + kw];
#pragma unroll
                    for (int q = 0; q < 4; ++q) {
                        acc0[q] += e0[q + kw] * fa + e1[q + kw] * fb;
                        acc1[q] += e1[q + kw] * fc + e0[q + kw] * fd;
                    }
                }
            }
            if (active) {
                const int orow = 4 * s + m;
                *(float4*)(o0 + orow * IMG_W + col) =
                    make_float4(acc0[0], acc0[1], acc0[2], acc0[3]);
                *(float4*)(o1 + orow * IMG_W + col) =
                    make_float4(acc1[0], acc1[1], acc1[2], acc1[3]);
            }
        }
    };

    // Software pipeline over batches g, g+8, g+16, g+24 with two buffers.
    float4 A0[6], A1[6], B0[6], B1[6];
    load_tile(g,          A0, A1);
    load_tile(g + GY,     B0, B1);
    compute_tile(g,          A0, A1);
    load_tile(g + 2 * GY, A0, A1);
    compute_tile(g + GY,     B0, B1);
    load_tile(g + 3 * GY, B0, B1);
    compute_tile(g + 2 * GY, A0, A1);
    compute_tile(g + 3 * GY, B0, B1);
}

extern "C" void kernel_launch(void* const* d_in, const int* in_sizes, int n_in,
                              void* d_out, int out_size, void* d_ws, size_t ws_size,
                              hipStream_t stream) {
    const float* x = (const float*)d_in[0];   // (32, 256, 56, 56) fp32
    const float* w = (const float*)d_in[1];   // (512, 1, 3, 3)   fp32
    float* out = (float*)d_out;               // (32, 256, 56, 56) fp32

    dim3 grid(IN_CH / 2, GY);   // 128 pairs x 8 batch-groups = 1024 blocks (4/CU)
    dim3 block(256);
    dwconv_butterfly<<<grid, block, 0, stream>>>(x, w, out);
}